// Round 13
// baseline (42.462 us; speedup 1.0000x reference)
//
#include <hip/hip_runtime.h>
#include <hip/hip_bf16.h>
#include <stdint.h>

// Problem constants
#define BB 16
#define SS 512
#define TT 16
#define DD 128
#define CH 64                 // s-rows per stage
#define NCH (SS/CH)           // 8
#define LN_EPS 1e-5f

typedef __attribute__((ext_vector_type(8))) short short8;
typedef __attribute__((ext_vector_type(4))) float f32x4;

// HW packed f32->bf16 (RNE): dst.lo = src0, dst.hi = src1
static __device__ __forceinline__ uint32_t cvt_pk_bf16(float lo, float hi) {
    uint32_t r;
    asm("v_cvt_pk_bf16_f32 %0, %1, %2" : "=v"(r) : "v"(lo), "v"(hi));
    return r;
}

// LDS-ordering barrier: does NOT drain vmcnt.
#define BAR() do {                                            \
    asm volatile("s_waitcnt lgkmcnt(0)" ::: "memory");        \
    __builtin_amdgcn_s_barrier();                             \
    asm volatile("" ::: "memory");                            \
} while (0)

// -----------------------------------------------------------------------------
// Single fused kernel, one block per (b,t), 512 threads = 8 waves (2/SIMD).
// Wave w owns output cols [w*16,w*16+16). Software-pipelined stages:
//   body(st): computePkg(st+1)  [GEMM+act+prefix+shuffles — hM-INDEPENDENT]
//           ∥ tail(st)          [hE = Ec*hM+Ev; 16 stores; hM = Mc*hM+Mv]
//           ∥ phaseLN(st+2)     [from register-prefetched x]
//           ∥ issuePx(st+3)
//           BAR
// Row permutation: LN writes s-row s to A-slot (mt*16+lhi*4+j), s=lhi*16+mt*4+j
// so each lane owns 16 consecutive s-rows (lane-local prefix, 5 shuffles/stage).
// -----------------------------------------------------------------------------
__global__ __launch_bounds__(512)
__attribute__((amdgpu_waves_per_eu(2, 2)))
void fused_mingru(
    const float* __restrict__ x, const float* __restrict__ prevh,
    const float* __restrict__ gamma, const float* __restrict__ beta,
    const float* __restrict__ W, const float* __restrict__ bias,
    float* __restrict__ out, float* __restrict__ nexth)
{
    __shared__ __align__(16) unsigned char xnb[2][CH*256];  // 2 x 16 KB bf16 xn

    const int tid  = threadIdx.x;
    const int w    = tid >> 6;           // 0..7
    const int lane = tid & 63;
    const int l15  = lane & 15;
    const int lhi  = lane >> 4;

    const int bt = blockIdx.x;
    const size_t rowstride = (size_t)TT * DD;               // 2048
    const size_t base_bt   = ((size_t)(bt >> 4) * SS * TT + (bt & 15)) * DD;

    // ---- LN lane assignment: 8 threads per row ----
    const int r_ln = tid >> 3;           // s-row 0..63 within chunk
    const int c8   = tid & 7;            // 16-float slot within the row
    const int slot_p = ((r_ln >> 2) & 3)*16 + (r_ln >> 4)*4 + (r_ln & 3);
    const int keyx   = slot_p & 7;
    const float* xp0 = x + base_bt + (size_t)r_ln * rowstride + c8*16;

    // ---- register prefetch of x chunk (16 VGPR), issue pinned ----
    f32x4 px0, px1, px2, px3;
    auto issuePx = [&](int st) {
        const float* xp = xp0 + (size_t)st * CH * rowstride;
        px0 = *(const f32x4*)(xp + 0);
        px1 = *(const f32x4*)(xp + 4);
        px2 = *(const f32x4*)(xp + 8);
        px3 = *(const f32x4*)(xp + 12);
        __builtin_amdgcn_sched_barrier(0);
    };
    issuePx(0);   // latency hidden under the W-fragment build

    // ---- build W fragments + folded bias in-kernel ----
    short8 wfr[2][4];
    float  bs2[2];
    #pragma unroll
    for (int ni = 0; ni < 2; ++ni) {
        const int col = (ni ? 128 : 0) + w*16 + l15;
        float acc = 0.0f;
        #pragma unroll
        for (int kt = 0; kt < 4; ++kt) {
            union { short8 s8; uint32_t u[4]; } fr;
            #pragma unroll
            for (int p = 0; p < 4; ++p) {
                const int k0 = kt*32 + lhi*8 + 2*p;
                const float w0 = W[(size_t)k0*256 + col];
                const float w1 = W[(size_t)(k0+1)*256 + col];
                acc = fmaf(beta[k0],   w0, acc);
                acc = fmaf(beta[k0+1], w1, acc);
                fr.u[p] = cvt_pk_bf16(gamma[k0]*w0, gamma[k0+1]*w1);
            }
            wfr[ni][kt] = fr.s8;
        }
        acc += __shfl_xor(acc, 16);
        acc += __shfl_xor(acc, 32);
        bs2[ni] = bias[col] + acc;
    }

    // running h for this wave's 16 columns (replicated across lhi groups)
    float hM = prevh[(size_t)bt*128 + w*16 + l15];

    // ---- LN: consume px regs -> xnb[st&1] at permuted slot (swizzled) ----
    auto phaseLN = [&](int st) {
        float s1 = px0.x+px0.y+px0.z+px0.w + px1.x+px1.y+px1.z+px1.w
                 + px2.x+px2.y+px2.z+px2.w + px3.x+px3.y+px3.z+px3.w;
        float s2 = px0.x*px0.x+px0.y*px0.y+px0.z*px0.z+px0.w*px0.w
                 + px1.x*px1.x+px1.y*px1.y+px1.z*px1.z+px1.w*px1.w
                 + px2.x*px2.x+px2.y*px2.y+px2.z*px2.z+px2.w*px2.w
                 + px3.x*px3.x+px3.y*px3.y+px3.z*px3.z+px3.w*px3.w;
        s1 += __shfl_xor(s1, 1); s2 += __shfl_xor(s2, 1);
        s1 += __shfl_xor(s1, 2); s2 += __shfl_xor(s2, 2);
        s1 += __shfl_xor(s1, 4); s2 += __shfl_xor(s2, 4);
        const float mu = s1 * (1.0f/128.0f);
        const float rs = rsqrtf(s2 * (1.0f/128.0f) - mu*mu + LN_EPS);
        unsigned char* row = xnb[st & 1] + slot_p*256;
        union { short8 s8; uint32_t u[4]; } a, b2;
        a.u[0]  = cvt_pk_bf16((px0.x-mu)*rs, (px0.y-mu)*rs);
        a.u[1]  = cvt_pk_bf16((px0.z-mu)*rs, (px0.w-mu)*rs);
        a.u[2]  = cvt_pk_bf16((px1.x-mu)*rs, (px1.y-mu)*rs);
        a.u[3]  = cvt_pk_bf16((px1.z-mu)*rs, (px1.w-mu)*rs);
        b2.u[0] = cvt_pk_bf16((px2.x-mu)*rs, (px2.y-mu)*rs);
        b2.u[1] = cvt_pk_bf16((px2.z-mu)*rs, (px2.w-mu)*rs);
        b2.u[2] = cvt_pk_bf16((px3.x-mu)*rs, (px3.y-mu)*rs);
        b2.u[3] = cvt_pk_bf16((px3.z-mu)*rs, (px3.w-mu)*rs);
        *(short8*)(row + (((2*c8)     ^ keyx) << 4)) = a.s8;
        *(short8*)(row + (((2*c8 + 1) ^ keyx) << 4)) = b2.s8;
    };

    // ---- package: everything hM-independent for one stage ----
    struct Pkg { float Cc[16], Cv[16], Ec, Ev, Mc, Mv; };
    Pkg pkA, pkB;

    auto computePkg = [&](int st, Pkg& P) {
        const unsigned char* xb = xnb[st & 1];
        #pragma unroll
        for (int mt = 0; mt < 4; ++mt) {
            const unsigned char* rowp = xb + (mt*16 + l15)*256;
            short8 af[4];
            #pragma unroll
            for (int kt = 0; kt < 4; ++kt) {
                const int c = (kt << 2) | lhi;
                af[kt] = *(const short8*)(rowp + ((c ^ (l15 & 7)) << 4));
            }
            f32x4 ag = (f32x4)(0.f), ah = (f32x4)(0.f);
            #pragma unroll
            for (int kt = 0; kt < 4; ++kt) {
                ag = __builtin_amdgcn_mfma_f32_16x16x32_bf16(af[kt], wfr[0][kt], ag, 0, 0, 0);
                ah = __builtin_amdgcn_mfma_f32_16x16x32_bf16(af[kt], wfr[1][kt], ah, 0, 0, 0);
            }
            #pragma unroll
            for (int j = 0; j < 4; ++j) {
                const float g  = ag[j] + bs2[0];
                const float hh = ah[j] + bs2[1];
                const float cc = 1.0f / (1.0f + __expf(g));
                const float ga = (hh >= 0.0f) ? (hh + 0.5f)
                                              : (1.0f / (1.0f + __expf(-hh)));
                P.Cc[mt*4 + j] = cc;
                P.Cv[mt*4 + j] = (1.0f - cc) * ga;
            }
        }
        #pragma unroll
        for (int i = 1; i < 16; ++i) {          // lane-local prefix, 16 rows
            P.Cv[i] = fmaf(P.Cc[i], P.Cv[i-1], P.Cv[i]);
            P.Cc[i] = P.Cc[i] * P.Cc[i-1];
        }
        float Ic = P.Cc[15], Iv = P.Cv[15];     // cross-lhi Hillis-Steele
        float pc = __shfl_up(Ic, 16), pv = __shfl_up(Iv, 16);
        if (lhi >= 1) { Iv = fmaf(Ic, pv, Iv); Ic *= pc; }
        pc = __shfl_up(Ic, 32); pv = __shfl_up(Iv, 32);
        if (lhi >= 2) { Iv = fmaf(Ic, pv, Iv); Ic *= pc; }
        float Ec = __shfl_up(Ic, 16), Ev = __shfl_up(Iv, 16);
        if (lhi == 0) { Ec = 1.0f; Ev = 0.0f; }
        P.Ec = Ec; P.Ev = Ev;
        P.Mc = __shfl(Ic, 48 + l15);
        P.Mv = __shfl(Iv, 48 + l15);
    };

    auto tail = [&](int st, Pkg& P) {
        const float hE = fmaf(P.Ec, hM, P.Ev);  // h before row lhi*16
        float* op = out + base_bt + (size_t)(st*CH + lhi*16) * rowstride + w*16 + l15;
        #pragma unroll
        for (int i = 0; i < 16; ++i)
            op[(size_t)i * rowstride] = fmaf(P.Cc[i], hE, P.Cv[i]);
        hM = fmaf(P.Mc, hM, P.Mv);
    };

    // ---- prologue ----
    phaseLN(0);                 // consumes px(0) -> xnb[0]
    issuePx(1);
    BAR();
    computePkg(0, pkA);         // reads xnb[0]
    phaseLN(1);                 // consumes px(1) -> xnb[1]
    issuePx(2);
    BAR();

    // ---- pipelined main loop: unrolled so A/B and branches fold ----
    #pragma unroll
    for (int s2 = 0; s2 < NCH; s2 += 2) {
        // even stage s2: current pkA, next into pkB
        if (s2 + 1 < NCH) computePkg(s2 + 1, pkB);
        tail(s2, pkA);
        if (s2 + 2 < NCH) phaseLN(s2 + 2);
        if (s2 + 3 < NCH) issuePx(s2 + 3);
        BAR();
        // odd stage s2+1: current pkB, next into pkA
        if (s2 + 2 < NCH) computePkg(s2 + 2, pkA);
        tail(s2 + 1, pkB);
        if (s2 + 3 < NCH) phaseLN(s2 + 3);
        if (s2 + 4 < NCH) issuePx(s2 + 4);
        BAR();
    }

    if (lane < 16)
        nexth[(size_t)bt*128 + w*16 + lane] = hM;
}

extern "C" void kernel_launch(void* const* d_in, const int* in_sizes, int n_in,
                              void* d_out, int out_size, void* d_ws, size_t ws_size,
                              hipStream_t stream) {
    const float* x     = (const float*)d_in[0];
    const float* prevh = (const float*)d_in[1];
    const float* gamma = (const float*)d_in[2];
    const float* beta  = (const float*)d_in[3];
    const float* W     = (const float*)d_in[4];
    const float* bias  = (const float*)d_in[5];

    float* out   = (float*)d_out;
    float* nexth = out + (size_t)BB*SS*TT*DD;              // 16777216

    fused_mingru<<<BB*TT, 512, 0, stream>>>(x, prevh, gamma, beta, W, bias,
                                            out, nexth);
}